// Round 8
// baseline (402.164 us; speedup 1.0000x reference)
//
#include <hip/hip_runtime.h>
#include <hip/hip_bf16.h>
#include <stdint.h>

#define NEXP 8
#define HD 1024
#define ID 3584
#define NTOK 2048
#define NSLOT 4096          // NTOK * TOPK
#define SLOT_PAD 128
#define NSLOT_ALLOC (NSLOT + SLOT_PAD)
#define KSPLIT 2
#define KLEN (ID / KSPLIT)    // 1792

typedef unsigned short u16;
typedef __attribute__((ext_vector_type(8))) short s16x8;
typedef __attribute__((ext_vector_type(4))) short s16x4;
typedef __attribute__((ext_vector_type(4))) float f32x4;

#define BARRIER() __builtin_amdgcn_s_barrier()
#define LGKM0()   asm volatile("s_waitcnt lgkmcnt(0)" ::: "memory")
#define VMCNT0()  asm volatile("s_waitcnt vmcnt(0)" ::: "memory")
#define SCHEDB()  __builtin_amdgcn_sched_barrier(0)

__device__ __forceinline__ u16 f2bf(float f) {
    __hip_bfloat16 h = __float2bfloat16(f);   // RNE
    union { __hip_bfloat16 h; u16 u; } v; v.h = h; return v.u;
}

__device__ __forceinline__ s16x8 cvt8(f32x4 a, f32x4 b) {
    s16x8 o;
    o[0]=(short)f2bf(a[0]); o[1]=(short)f2bf(a[1]); o[2]=(short)f2bf(a[2]); o[3]=(short)f2bf(a[3]);
    o[4]=(short)f2bf(b[0]); o[5]=(short)f2bf(b[1]); o[6]=(short)f2bf(b[2]); o[7]=(short)f2bf(b[3]);
    return o;
}

__device__ __forceinline__ void glds16(const void* g, void* l) {
    __builtin_amdgcn_global_load_lds((const __attribute__((address_space(1))) unsigned*)g,
                                     (__attribute__((address_space(3))) unsigned*)l, 16, 0, 0);
}

// ---------------- K0: zero counters ----------------
__global__ void init_kernel(int* __restrict__ counts) {
    if (threadIdx.x < 16) counts[threadIdx.x] = 0;   // counts[8] + counts2[8]
}

// ---------------- K1: router (fp32, exact top-2) ----------------
__global__ void router_kernel(const float* __restrict__ x, const float* __restrict__ wg,
                              int* __restrict__ topk_idx, float* __restrict__ topk_w,
                              int* __restrict__ counts) {
    int t = blockIdx.x;
    int lane = threadIdx.x;   // 64 threads = 1 wave
    const float* xr = x + (size_t)t * HD;
    float acc[NEXP];
#pragma unroll
    for (int e = 0; e < NEXP; ++e) acc[e] = 0.f;
#pragma unroll
    for (int i = 0; i < HD / 256; ++i) {
        int h = i * 256 + lane * 4;
        f32x4 xv = *(const f32x4*)(xr + h);
#pragma unroll
        for (int e = 0; e < NEXP; ++e) {
            f32x4 wv = *(const f32x4*)(wg + e * HD + h);
            acc[e] += xv[0]*wv[0] + xv[1]*wv[1] + xv[2]*wv[2] + xv[3]*wv[3];
        }
    }
#pragma unroll
    for (int e = 0; e < NEXP; ++e) {
#pragma unroll
        for (int s = 32; s > 0; s >>= 1) acc[e] += __shfl_xor(acc[e], s, 64);
    }
    if (lane == 0) {
        int b0 = 0; float l0 = acc[0];
#pragma unroll
        for (int e = 1; e < NEXP; ++e) if (acc[e] > l0) { l0 = acc[e]; b0 = e; }
        int b1 = (b0 == 0) ? 1 : 0; float l1 = acc[b1];
#pragma unroll
        for (int e = 0; e < NEXP; ++e) {
            if (e == b0 || e == b1) continue;
            if (acc[e] > l1) { l1 = acc[e]; b1 = e; }
        }
        float w0 = 1.f / (1.f + expf(l1 - l0));   // renormalized top-2 softmax
        float w1 = 1.f - w0;
        topk_idx[2 * t] = b0; topk_idx[2 * t + 1] = b1;
        topk_w[2 * t] = w0;  topk_w[2 * t + 1] = w1;
        atomicAdd(&counts[b0], 1);
        atomicAdd(&counts[b1], 1);
    }
}

// ---------------- K2: exclusive scan + pad rows ----------------
__global__ void scan_kernel(const int* __restrict__ counts, int* __restrict__ offsets,
                            int* __restrict__ rows) {
    if (threadIdx.x == 0) {
        int off = 0;
#pragma unroll
        for (int e = 0; e < NEXP; ++e) { offsets[e] = off; off += counts[e]; }
    }
    if (threadIdx.x < SLOT_PAD) rows[NSLOT + threadIdx.x] = 0;
}

// ---------------- K3: slot assignment ----------------
__global__ void assign_kernel(const int* __restrict__ topk_idx, const int* __restrict__ offsets,
                              int* __restrict__ counts2, int* __restrict__ rows,
                              int* __restrict__ slot_of) {
    int i = blockIdx.x * 256 + threadIdx.x;   // 0..4095
    int e = topk_idx[i];
    int pos = atomicAdd(&counts2[e], 1);
    int slot = offsets[e] + pos;
    rows[slot] = i >> 1;       // token id
    slot_of[i] = slot;
}

// ---------------- K4: x fp32 -> bf16 ----------------
__global__ __launch_bounds__(256)
void cvt_bf_kernel(const float* __restrict__ src, u16* __restrict__ dst, int n8) {
    int stride = gridDim.x * 256;
    for (int i = blockIdx.x * 256 + threadIdx.x; i < n8; i += stride) {
        f32x4 v0 = ((const f32x4*)src)[2 * i];
        f32x4 v1 = ((const f32x4*)src)[2 * i + 1];
        ((s16x8*)dst)[i] = cvt8(v0, v1);
    }
}

// ---------------- K5: fused GEMM1 (g,u) + SwiGLU -> h (bf16), fp32 weights in-kernel ----------------
// A: glds from xbf (bf16), double-buffered. B: reg-staged from w1/w3 FP32 with in-register
// cvt (T14 split: loads issued before MFMA, cvt+swizzled ds_write after barrier).
// Read-side swizzle identical to R6 (verified SQ_LDS_BANK_CONFLICT = 0).
#define G1_BLOCKS (NEXP * (NTOK / 128) * (ID / 128))   // 3584
__global__ __launch_bounds__(256, 2)
void gemm1_kernel(const u16* __restrict__ xbf, const float* __restrict__ w1,
                  const float* __restrict__ w3, const int* __restrict__ counts,
                  const int* __restrict__ offsets, const int* __restrict__ rows,
                  u16* __restrict__ hbuf) {
    __shared__ u16 As[2][128][32];   // 16 KB (dbuf for glds)
    __shared__ u16 B1s[128][32];     //  8 KB
    __shared__ u16 B3s[128][32];     //  8 KB

    const int NT = ID / 128;      // 28
    int bid = blockIdx.x;
    int e = bid / (16 * NT);
    int rem = bid - e * (16 * NT);
    int mt = rem / NT;
    int nt = rem - mt * NT;
    int n_e = counts[e];
    int m0 = mt * 128;
    if (m0 >= n_e) return;
    int off = offsets[e];
    int n0 = nt * 128;

    int tid = threadIdx.x;
    int lane = tid & 63;
    int wid = tid >> 6;

    // ---- A staging (glds, pre-swizzled source granule) ----
    int srow = wid * 32 + (lane >> 2);
    int chunk = ((lane & 3) ^ ((srow >> 1) & 3)) * 8;
    int tokA0 = rows[off + m0 + srow];
    int tokA1 = rows[off + m0 + srow + 16];
    const u16* srcA0 = xbf + (size_t)tokA0 * HD + chunk;
    const u16* srcA1 = xbf + (size_t)tokA1 * HD + chunk;

    // ---- B staging (fp32 -> regs -> cvt -> swizzled ds_write) ----
    int brow = tid >> 1;               // 0..127
    int kh   = (tid & 1) * 16;         // k offset within BK=32
    int bs0  = (tid & 1) * 2;          // first logical granule
    int swzb = (brow >> 1) & 3;
    int g0 = (bs0 ^ swzb) * 8, g1 = ((bs0 + 1) ^ swzb) * 8;
    const float* pB1 = w1 + ((size_t)e * ID + n0 + brow) * HD + kh;
    const float* pB3 = w3 + ((size_t)e * ID + n0 + brow) * HD + kh;

    f32x4 accg[4][4] = {}, accu[4][4] = {};
    int wm = (wid >> 1) * 64, wn = (wid & 1) * 64;
    int lr = lane & 15;
    int k8sw = ((lane >> 4) ^ ((lr >> 1) & 3)) * 8;   // inverse swizzle on ds_read

    f32x4 rb1[4], rb3[4];
#define LOADB(kn)                                                            \
    do {                                                                     \
        const float* p1 = pB1 + (kn); const float* p3 = pB3 + (kn);         \
        rb1[0] = *(const f32x4*)(p1);      rb1[1] = *(const f32x4*)(p1+4);  \
        rb1[2] = *(const f32x4*)(p1+8);    rb1[3] = *(const f32x4*)(p1+12); \
        rb3[0] = *(const f32x4*)(p3);      rb3[1] = *(const f32x4*)(p3+4);  \
        rb3[2] = *(const f32x4*)(p3+8);    rb3[3] = *(const f32x4*)(p3+12); \
    } while (0)
#define WRITEB()                                          \
    do {                                                  \
        *(s16x8*)&B1s[brow][g0] = cvt8(rb1[0], rb1[1]);   \
        *(s16x8*)&B1s[brow][g1] = cvt8(rb1[2], rb1[3]);   \
        *(s16x8*)&B3s[brow][g0] = cvt8(rb3[0], rb3[1]);   \
        *(s16x8*)&B3s[brow][g1] = cvt8(rb3[2], rb3[3]);   \
    } while (0)

    // prologue: tile 0
    glds16(srcA0, &As[0][wid * 32][0]);
    glds16(srcA1, &As[0][wid * 32 + 16][0]);
    LOADB(0);
    VMCNT0();
    WRITEB();
    LGKM0();
    BARRIER();

    const int NIT = HD / 32;  // 32
#pragma unroll 2
    for (int it = 0; it < NIT; ++it) {
        int cur = it & 1;
        if (it + 1 < NIT) {   // issue next-tile loads EARLY (hide under MFMA)
            int kn = (it + 1) * 32;
            glds16(srcA0 + kn, &As[cur ^ 1][wid * 32][0]);
            glds16(srcA1 + kn, &As[cur ^ 1][wid * 32 + 16][0]);
            LOADB(kn);
        }
        s16x8 a[4], b1[4], b3[4];
#pragma unroll
        for (int f = 0; f < 4; ++f) {
            a[f]  = *(const s16x8*)&As[cur][wm + f * 16 + lr][k8sw];
            b1[f] = *(const s16x8*)&B1s[wn + f * 16 + lr][k8sw];
            b3[f] = *(const s16x8*)&B3s[wn + f * 16 + lr][k8sw];
        }
#pragma unroll
        for (int fm = 0; fm < 4; ++fm)
#pragma unroll
            for (int fn = 0; fn < 4; ++fn) {
                accg[fm][fn] = __builtin_amdgcn_mfma_f32_16x16x32_bf16(a[fm], b1[fn], accg[fm][fn], 0, 0, 0);
                accu[fm][fn] = __builtin_amdgcn_mfma_f32_16x16x32_bf16(a[fm], b3[fn], accu[fm][fn], 0, 0, 0);
            }
        SCHEDB();
        BARRIER();            // all waves done reading B1s/B3s
        if (it + 1 < NIT) {
            VMCNT0();         // B regs + next A glds landed (issued ~full iter ago)
            WRITEB();
            LGKM0();
        }
        BARRIER();            // B(it+1) + As[nxt] published
        SCHEDB();
    }

    // epilogue: SwiGLU + bf16 store
    int lc = lane & 15;
    int lr4 = (lane >> 4) * 4;
#pragma unroll
    for (int fm = 0; fm < 4; ++fm) {
#pragma unroll
        for (int r = 0; r < 4; ++r) {
            int row = wm + fm * 16 + lr4 + r;
            if (m0 + row < n_e) {
                size_t base = (size_t)(off + m0 + row) * ID + n0 + wn;
#pragma unroll
                for (int fn = 0; fn < 4; ++fn) {
                    float g = accg[fm][fn][r];
                    float u = accu[fm][fn][r];
                    float hv = g * u / (1.f + expf(-g));   // silu(g)*u
                    hbuf[base + fn * 16 + lc] = f2bf(hv);
                }
            }
        }
    }
}

// ---------------- K6: GEMM2 h @ w2^T (fp32 in-kernel) -> per-slot fp32, split-K x2 ----------------
__global__ __launch_bounds__(256, 2)
void gemm2_kernel(const u16* __restrict__ hbuf, const float* __restrict__ w2,
                  const int* __restrict__ counts, const int* __restrict__ offsets,
                  float* __restrict__ out2) {
    __shared__ u16 As[2][128][32];   // 16 KB
    __shared__ u16 Bs[128][32];      //  8 KB

    const int NT = HD / 128;      // 8
    int bid = blockIdx.x;
    int e = bid / (16 * NT * KSPLIT);
    int rem = bid - e * (16 * NT * KSPLIT);
    int mt = rem / (NT * KSPLIT);
    int rem2 = rem - mt * (NT * KSPLIT);
    int nt = rem2 / KSPLIT;
    int ks = rem2 - nt * KSPLIT;
    int n_e = counts[e];
    int m0 = mt * 128;
    if (m0 >= n_e) return;
    int off = offsets[e];
    int n0 = nt * 128;
    int kbase = ks * KLEN;

    int tid = threadIdx.x;
    int lane = tid & 63;
    int wid = tid >> 6;

    int srow = wid * 32 + (lane >> 2);
    int chunk = ((lane & 3) ^ ((srow >> 1) & 3)) * 8;
    const u16* srcA0 = hbuf + (size_t)(off + m0 + srow) * ID + kbase + chunk;
    const u16* srcA1 = srcA0 + (size_t)16 * ID;

    int brow = tid >> 1;
    int kh   = (tid & 1) * 16;
    int bs0  = (tid & 1) * 2;
    int swzb = (brow >> 1) & 3;
    int g0 = (bs0 ^ swzb) * 8, g1 = ((bs0 + 1) ^ swzb) * 8;
    const float* pB = w2 + ((size_t)e * HD + n0 + brow) * ID + kbase + kh;

    f32x4 acc[4][4] = {};
    int wm = (wid >> 1) * 64, wn = (wid & 1) * 64;
    int lr = lane & 15;
    int k8sw = ((lane >> 4) ^ ((lr >> 1) & 3)) * 8;

    f32x4 rb[4];
#define LOADB2(kn)                                                       \
    do {                                                                 \
        const float* p = pB + (kn);                                      \
        rb[0] = *(const f32x4*)(p);      rb[1] = *(const f32x4*)(p+4);  \
        rb[2] = *(const f32x4*)(p+8);    rb[3] = *(const f32x4*)(p+12); \
    } while (0)
#define WRITEB2()                                      \
    do {                                               \
        *(s16x8*)&Bs[brow][g0] = cvt8(rb[0], rb[1]);   \
        *(s16x8*)&Bs[brow][g1] = cvt8(rb[2], rb[3]);   \
    } while (0)

    glds16(srcA0, &As[0][wid * 32][0]);
    glds16(srcA1, &As[0][wid * 32 + 16][0]);
    LOADB2(0);
    VMCNT0();
    WRITEB2();
    LGKM0();
    BARRIER();

    const int NIT = KLEN / 32;  // 56
#pragma unroll 2
    for (int it = 0; it < NIT; ++it) {
        int cur = it & 1;
        if (it + 1 < NIT) {
            int kn = (it + 1) * 32;
            glds16(srcA0 + kn, &As[cur ^ 1][wid * 32][0]);
            glds16(srcA1 + kn, &As[cur ^ 1][wid * 32 + 16][0]);
            LOADB2(kn);
        }
        s16x8 a[4], b[4];
#pragma unroll
        for (int f = 0; f < 4; ++f) {
            a[f] = *(const s16x8*)&As[cur][wm + f * 16 + lr][k8sw];
            b[f] = *(const s16x8*)&Bs[wn + f * 16 + lr][k8sw];
        }
#pragma unroll
        for (int fm = 0; fm < 4; ++fm)
#pragma unroll
            for (int fn = 0; fn < 4; ++fn)
                acc[fm][fn] = __builtin_amdgcn_mfma_f32_16x16x32_bf16(a[fm], b[fn], acc[fm][fn], 0, 0, 0);
        SCHEDB();
        BARRIER();
        if (it + 1 < NIT) {
            VMCNT0();
            WRITEB2();
            LGKM0();
        }
        BARRIER();
        SCHEDB();
    }

    float* outp = out2 + (size_t)ks * NSLOT_ALLOC * HD;
    int lc = lane & 15;
    int lr4 = (lane >> 4) * 4;
#pragma unroll
    for (int fm = 0; fm < 4; ++fm) {
#pragma unroll
        for (int r = 0; r < 4; ++r) {
            int row = wm + fm * 16 + lr4 + r;
            if (m0 + row < n_e) {
                float* dst = outp + (size_t)(off + m0 + row) * HD + n0 + wn;
#pragma unroll
                for (int fn = 0; fn < 4; ++fn)
                    dst[fn * 16 + lc] = acc[fm][fn][r];
            }
        }
    }
}

// ---------------- K7: weighted combine (sums KSPLIT partials) ----------------
__global__ void combine_kernel(const float* __restrict__ out2, const int* __restrict__ slot_of,
                               const float* __restrict__ topk_w, float* __restrict__ y) {
    int i = blockIdx.x * 256 + threadIdx.x;   // over NTOK*HD/4
    int t = i >> 8;           // HD/4 = 256 float4 per token
    int c = i & 255;
    int s0 = slot_of[2 * t], s1 = slot_of[2 * t + 1];
    float w0 = topk_w[2 * t], w1 = topk_w[2 * t + 1];
    f32x4 o = {0.f, 0.f, 0.f, 0.f};
#pragma unroll
    for (int ks = 0; ks < KSPLIT; ++ks) {
        const float* p = out2 + (size_t)ks * NSLOT_ALLOC * HD;
        f32x4 a = ((const f32x4*)(p + (size_t)s0 * HD))[c];
        f32x4 b = ((const f32x4*)(p + (size_t)s1 * HD))[c];
#pragma unroll
        for (int j = 0; j < 4; ++j) o[j] += w0 * a[j] + w1 * b[j];
    }
    ((f32x4*)(y + (size_t)t * HD))[c] = o;
}

extern "C" void kernel_launch(void* const* d_in, const int* in_sizes, int n_in,
                              void* d_out, int out_size, void* d_ws, size_t ws_size,
                              hipStream_t stream) {
    (void)in_sizes; (void)n_in; (void)out_size; (void)ws_size;
    const float* x  = (const float*)d_in[0];
    const float* wg = (const float*)d_in[1];
    const float* w1 = (const float*)d_in[2];
    const float* w3 = (const float*)d_in[3];
    const float* w2 = (const float*)d_in[4];
    float* y = (float*)d_out;

    char* ws = (char*)d_ws;
    int*   counts   = (int*)(ws + 0);       // 8 ints
    int*   counts2  = (int*)(ws + 32);      // 8 ints
    int*   offsets  = (int*)(ws + 64);      // 8 ints
    int*   topk_idx = (int*)(ws + 128);                        // 4096 ints
    float* topk_w   = (float*)(ws + 128 + (size_t)NSLOT * 4);  // 4096 floats
    int*   rows     = (int*)(ws + 128 + (size_t)NSLOT * 8);    // 4224 ints
    int*   slot_of  = (int*)(ws + 128 + (size_t)NSLOT * 8 + (size_t)NSLOT_ALLOC * 4);
    size_t off_xbf = 128 + (size_t)NSLOT * 12 + (size_t)NSLOT_ALLOC * 4;
    off_xbf = (off_xbf + 255) & ~(size_t)255;
    u16* xbf = (u16*)(ws + off_xbf);
    size_t off_h = off_xbf + (size_t)NTOK * HD * 2;
    u16* hbuf = (u16*)(ws + off_h);
    size_t off_o2 = off_h + (size_t)NSLOT_ALLOC * ID * 2;
    off_o2 = (off_o2 + 255) & ~(size_t)255;
    float* out2 = (float*)(ws + off_o2);    // KSPLIT partial buffers

    init_kernel<<<1, 64, 0, stream>>>(counts);
    router_kernel<<<NTOK, 64, 0, stream>>>(x, wg, topk_idx, topk_w, counts);
    scan_kernel<<<1, 128, 0, stream>>>(counts, offsets, rows);
    assign_kernel<<<NSLOT / 256, 256, 0, stream>>>(topk_idx, offsets, counts2, rows, slot_of);
    cvt_bf_kernel<<<512, 256, 0, stream>>>(x, xbf, NTOK * HD / 8);
    gemm1_kernel<<<G1_BLOCKS, 256, 0, stream>>>(xbf, w1, w3, counts, offsets, rows, hbuf);
    gemm2_kernel<<<NEXP * (NTOK / 128) * (HD / 128) * KSPLIT, 256, 0, stream>>>(hbuf, w2, counts, offsets, out2);
    combine_kernel<<<(NTOK * HD / 4) / 256, 256, 0, stream>>>(out2, slot_of, topk_w, y);
}

// Round 9
// 345.202 us; speedup vs baseline: 1.1650x; 1.1650x over previous
//
#include <hip/hip_runtime.h>
#include <hip/hip_bf16.h>
#include <stdint.h>

#define NEXP 8
#define HD 1024
#define ID 3584
#define NTOK 2048
#define NSLOT 4096          // NTOK * TOPK
#define SLOT_PAD 128
#define NSLOT_ALLOC (NSLOT + SLOT_PAD)
#define WN (NEXP * ID * HD)   // elements per weight tensor = 29,360,128
#define KSPLIT 4
#define KLEN (ID / KSPLIT)    // 896

typedef unsigned short u16;
typedef __attribute__((ext_vector_type(8))) short s16x8;
typedef __attribute__((ext_vector_type(4))) short s16x4;
typedef __attribute__((ext_vector_type(4))) float f32x4;

__device__ __forceinline__ u16 f2bf(float f) {
    __hip_bfloat16 h = __float2bfloat16(f);   // RNE
    union { __hip_bfloat16 h; u16 u; } v; v.h = h; return v.u;
}

__device__ __forceinline__ s16x8 cvt8(f32x4 a, f32x4 b) {
    s16x8 o;
    o[0]=(short)f2bf(a[0]); o[1]=(short)f2bf(a[1]); o[2]=(short)f2bf(a[2]); o[3]=(short)f2bf(a[3]);
    o[4]=(short)f2bf(b[0]); o[5]=(short)f2bf(b[1]); o[6]=(short)f2bf(b[2]); o[7]=(short)f2bf(b[3]);
    return o;
}

__device__ __forceinline__ void glds16(const void* g, void* l) {
    __builtin_amdgcn_global_load_lds((const __attribute__((address_space(1))) unsigned*)g,
                                     (__attribute__((address_space(3))) unsigned*)l, 16, 0, 0);
}

// ---------------- K0: zero counters ----------------
__global__ void init_kernel(int* __restrict__ counts) {
    if (threadIdx.x < 16) counts[threadIdx.x] = 0;   // counts[8] + counts2[8]
}

// ---------------- K1: router (fp32, exact top-2) ----------------
__global__ void router_kernel(const float* __restrict__ x, const float* __restrict__ wg,
                              int* __restrict__ topk_idx, float* __restrict__ topk_w,
                              int* __restrict__ counts) {
    int t = blockIdx.x;
    int lane = threadIdx.x;   // 64 threads = 1 wave
    const float* xr = x + (size_t)t * HD;
    float acc[NEXP];
#pragma unroll
    for (int e = 0; e < NEXP; ++e) acc[e] = 0.f;
#pragma unroll
    for (int i = 0; i < HD / 256; ++i) {
        int h = i * 256 + lane * 4;
        f32x4 xv = *(const f32x4*)(xr + h);
#pragma unroll
        for (int e = 0; e < NEXP; ++e) {
            f32x4 wv = *(const f32x4*)(wg + e * HD + h);
            acc[e] += xv[0]*wv[0] + xv[1]*wv[1] + xv[2]*wv[2] + xv[3]*wv[3];
        }
    }
#pragma unroll
    for (int e = 0; e < NEXP; ++e) {
#pragma unroll
        for (int s = 32; s > 0; s >>= 1) acc[e] += __shfl_xor(acc[e], s, 64);
    }
    if (lane == 0) {
        int b0 = 0; float l0 = acc[0];
#pragma unroll
        for (int e = 1; e < NEXP; ++e) if (acc[e] > l0) { l0 = acc[e]; b0 = e; }
        int b1 = (b0 == 0) ? 1 : 0; float l1 = acc[b1];
#pragma unroll
        for (int e = 0; e < NEXP; ++e) {
            if (e == b0 || e == b1) continue;
            if (acc[e] > l1) { l1 = acc[e]; b1 = e; }
        }
        float w0 = 1.f / (1.f + expf(l1 - l0));   // renormalized top-2 softmax
        float w1 = 1.f - w0;
        topk_idx[2 * t] = b0; topk_idx[2 * t + 1] = b1;
        topk_w[2 * t] = w0;  topk_w[2 * t + 1] = w1;
        atomicAdd(&counts[b0], 1);
        atomicAdd(&counts[b1], 1);
    }
}

// ---------------- K2: exclusive scan + pad rows ----------------
__global__ void scan_kernel(const int* __restrict__ counts, int* __restrict__ offsets,
                            int* __restrict__ rows) {
    if (threadIdx.x == 0) {
        int off = 0;
#pragma unroll
        for (int e = 0; e < NEXP; ++e) { offsets[e] = off; off += counts[e]; }
    }
    if (threadIdx.x < SLOT_PAD) rows[NSLOT + threadIdx.x] = 0;
}

// ---------------- K3: slot assignment ----------------
__global__ void assign_kernel(const int* __restrict__ topk_idx, const int* __restrict__ offsets,
                              int* __restrict__ counts2, int* __restrict__ rows,
                              int* __restrict__ slot_of) {
    int i = blockIdx.x * 256 + threadIdx.x;   // 0..4095
    int e = topk_idx[i];
    int pos = atomicAdd(&counts2[e], 1);
    int slot = offsets[e] + pos;
    rows[slot] = i >> 1;       // token id
    slot_of[i] = slot;
}

// ---------------- K4: fused fp32->bf16 for x, w1, w3 (one dispatch) ----------------
__global__ __launch_bounds__(256)
void cvt3_kernel(const float* __restrict__ x, u16* __restrict__ xbf,
                 const float* __restrict__ w1, u16* __restrict__ w1bf,
                 const float* __restrict__ w3, u16* __restrict__ w3bf) {
    const int NX = NTOK * HD / 8, NW = WN / 8;
    int stride = gridDim.x * 256;
    for (int i = blockIdx.x * 256 + threadIdx.x; i < NX + 2 * NW; i += stride) {
        const float* s; u16* d; int j;
        if (i < NX)            { s = x;  d = xbf;  j = i; }
        else if (i < NX + NW)  { s = w1; d = w1bf; j = i - NX; }
        else                   { s = w3; d = w3bf; j = i - NX - NW; }
        f32x4 v0 = ((const f32x4*)s)[2 * j];
        f32x4 v1 = ((const f32x4*)s)[2 * j + 1];
        ((s16x8*)d)[j] = cvt8(v0, v1);
    }
}

// ---------------- K5: FAT kernel: fused GEMM1 (g,u)+SwiGLU -> h  ||  w2 fp32->bf16 ----------------
// R6 structure (single-buffer, verified zero-conflict swizzle) + T1 panel-XCD remap:
// all 16 mt-blocks of one (e,nt) weight panel share bid%8 -> same XCD -> panel fetched
// once per XCD instead of ~2x (R6 FETCH 218 MB, ideal ~121 MB).
#define G1_BLOCKS (NEXP * (NTOK / 128) * (ID / 128))   // 3584
#define CVT2_BLOCKS 1024
__global__ __launch_bounds__(256, 2)
void gemm1_kernel(const u16* __restrict__ xbf, const u16* __restrict__ w1bf,
                  const u16* __restrict__ w3bf, const int* __restrict__ counts,
                  const int* __restrict__ offsets, const int* __restrict__ rows,
                  u16* __restrict__ hbuf,
                  const float* __restrict__ w2, u16* __restrict__ w2bf) {
    __shared__ u16 As[128][32];    // 8 KB
    __shared__ u16 B1s[128][32];   // 8 KB
    __shared__ u16 B3s[128][32];   // 8 KB

    if (blockIdx.x >= G1_BLOCKS) {
        // ---- side job: convert w2 to bf16 (overlaps with GEMM1 blocks) ----
        const int stride = CVT2_BLOCKS * 256;
        for (int i = (blockIdx.x - G1_BLOCKS) * 256 + threadIdx.x; i < WN / 8; i += stride) {
            f32x4 v0 = ((const f32x4*)w2)[2 * i];
            f32x4 v1 = ((const f32x4*)w2)[2 * i + 1];
            ((s16x8*)w2bf)[i] = cvt8(v0, v1);
        }
        return;
    }

    // T1 panel-XCD decode: panel g = gq*8 + (bid&7), rows-tile mt = (bid>>3)&15.
    // Same panel (fixed g) => fixed bid%8 => same XCD for all 16 mt-blocks.
    int bid = blockIdx.x;
    int gq = bid >> 7;            // 0..27
    int rm = bid & 127;
    int mt = rm >> 3;             // 0..15
    int g  = gq * 8 + (rm & 7);   // 0..223
    int e  = g / 28;              // NT = ID/128 = 28
    int nt = g - e * 28;

    int n_e = counts[e];
    int m0 = mt * 128;
    if (m0 >= n_e) return;
    int off = offsets[e];
    int n0 = nt * 128;

    int tid = threadIdx.x;
    int lane = tid & 63;
    int wid = tid >> 6;

    // staging: wave wid stages rows [32*wid,32*wid+32); physical granule lane&3,
    // source granule (lane&3) ^ ((srow>>1)&3)  (T2 swizzle via pre-swizzled global src)
    int srow = wid * 32 + (lane >> 2);
    int chunk = ((lane & 3) ^ ((srow >> 1) & 3)) * 8;

    int tokA0 = rows[off + m0 + srow];
    int tokA1 = rows[off + m0 + srow + 16];
    const u16* srcA0 = xbf + (size_t)tokA0 * HD + chunk;
    const u16* srcA1 = xbf + (size_t)tokA1 * HD + chunk;
    const u16* srcB1a = w1bf + ((size_t)e * ID + n0 + srow) * HD + chunk;
    const u16* srcB1b = srcB1a + (size_t)16 * HD;
    const u16* srcB3a = w3bf + ((size_t)e * ID + n0 + srow) * HD + chunk;
    const u16* srcB3b = srcB3a + (size_t)16 * HD;

    f32x4 accg[4][4] = {}, accu[4][4] = {};
    int wm = (wid >> 1) * 64, wn = (wid & 1) * 64;
    int lr = lane & 15;
    int k8sw = ((lane >> 4) ^ ((lr >> 1) & 3)) * 8;   // inverse swizzle on ds_read

    for (int k0 = 0; k0 < HD; k0 += 32) {
        glds16(srcA0 + k0,  &As[wid * 32][0]);
        glds16(srcA1 + k0,  &As[wid * 32 + 16][0]);
        glds16(srcB1a + k0, &B1s[wid * 32][0]);
        glds16(srcB1b + k0, &B1s[wid * 32 + 16][0]);
        glds16(srcB3a + k0, &B3s[wid * 32][0]);
        glds16(srcB3b + k0, &B3s[wid * 32 + 16][0]);
        __syncthreads();
        s16x8 a[4], b1[4], b3[4];
#pragma unroll
        for (int f = 0; f < 4; ++f) {
            a[f]  = *(const s16x8*)&As[wm + f * 16 + lr][k8sw];
            b1[f] = *(const s16x8*)&B1s[wn + f * 16 + lr][k8sw];
            b3[f] = *(const s16x8*)&B3s[wn + f * 16 + lr][k8sw];
        }
#pragma unroll
        for (int fm = 0; fm < 4; ++fm)
#pragma unroll
            for (int fn = 0; fn < 4; ++fn) {
                accg[fm][fn] = __builtin_amdgcn_mfma_f32_16x16x32_bf16(a[fm], b1[fn], accg[fm][fn], 0, 0, 0);
                accu[fm][fn] = __builtin_amdgcn_mfma_f32_16x16x32_bf16(a[fm], b3[fn], accu[fm][fn], 0, 0, 0);
            }
        __syncthreads();
    }

    // epilogue: SwiGLU + bf16 store
    int lc = lane & 15;
    int lr4 = (lane >> 4) * 4;
#pragma unroll
    for (int fm = 0; fm < 4; ++fm) {
#pragma unroll
        for (int r = 0; r < 4; ++r) {
            int row = wm + fm * 16 + lr4 + r;
            if (m0 + row < n_e) {
                size_t base = (size_t)(off + m0 + row) * ID + n0 + wn;
#pragma unroll
                for (int fn = 0; fn < 4; ++fn) {
                    float g2 = accg[fm][fn][r];
                    float u = accu[fm][fn][r];
                    float hv = g2 * u / (1.f + expf(-g2));   // silu(g)*u
                    hbuf[base + fn * 16 + lc] = f2bf(hv);
                }
            }
        }
    }
}

// ---------------- K6: GEMM2 h @ w2bf^T -> per-slot fp32, split-K x4 ----------------
// T1 expert-XCD remap: bid%8 = e -> XCD x owns expert x; w2_e and hbuf_e fetched ~once.
__global__ __launch_bounds__(256, 2)
void gemm2_kernel(const u16* __restrict__ hbuf, const u16* __restrict__ w2bf,
                  const int* __restrict__ counts, const int* __restrict__ offsets,
                  float* __restrict__ out2) {
    int bid = blockIdx.x;
    int e = bid & 7;
    int inner = bid >> 3;        // 0..511
    int mt = inner >> 5;         // 0..15  (8 nt * 4 ks = 32)
    int r2 = inner & 31;
    int nt = r2 >> 2;            // 0..7
    int ks = r2 & 3;             // 0..3

    int n_e = counts[e];
    int m0 = mt * 128;
    if (m0 >= n_e) return;
    int off = offsets[e];
    int n0 = nt * 128;
    int kbase = ks * KLEN;

    __shared__ u16 As[128][32];   // 8 KB
    __shared__ u16 Bs[128][32];   // 8 KB

    int tid = threadIdx.x;
    int lane = tid & 63;
    int wid = tid >> 6;

    int srow = wid * 32 + (lane >> 2);
    int chunk = ((lane & 3) ^ ((srow >> 1) & 3)) * 8;
    const u16* srcA0 = hbuf + (size_t)(off + m0 + srow) * ID + kbase + chunk;
    const u16* srcA1 = srcA0 + (size_t)16 * ID;
    const u16* srcB0 = w2bf + ((size_t)e * HD + n0 + srow) * ID + kbase + chunk;
    const u16* srcB1 = srcB0 + (size_t)16 * ID;

    f32x4 acc[4][4] = {};
    int wm = (wid >> 1) * 64, wn = (wid & 1) * 64;
    int lr = lane & 15;
    int k8sw = ((lane >> 4) ^ ((lr >> 1) & 3)) * 8;

    for (int k0 = 0; k0 < KLEN; k0 += 32) {
        glds16(srcA0 + k0, &As[wid * 32][0]);
        glds16(srcA1 + k0, &As[wid * 32 + 16][0]);
        glds16(srcB0 + k0, &Bs[wid * 32][0]);
        glds16(srcB1 + k0, &Bs[wid * 32 + 16][0]);
        __syncthreads();
        s16x8 a[4], b[4];
#pragma unroll
        for (int f = 0; f < 4; ++f) {
            a[f] = *(const s16x8*)&As[wm + f * 16 + lr][k8sw];
            b[f] = *(const s16x8*)&Bs[wn + f * 16 + lr][k8sw];
        }
#pragma unroll
        for (int fm = 0; fm < 4; ++fm)
#pragma unroll
            for (int fn = 0; fn < 4; ++fn)
                acc[fm][fn] = __builtin_amdgcn_mfma_f32_16x16x32_bf16(a[fm], b[fn], acc[fm][fn], 0, 0, 0);
        __syncthreads();
    }

    float* outp = out2 + (size_t)ks * NSLOT_ALLOC * HD;
    int lc = lane & 15;
    int lr4 = (lane >> 4) * 4;
#pragma unroll
    for (int fm = 0; fm < 4; ++fm) {
#pragma unroll
        for (int r = 0; r < 4; ++r) {
            int row = wm + fm * 16 + lr4 + r;
            if (m0 + row < n_e) {
                float* dst = outp + (size_t)(off + m0 + row) * HD + n0 + wn;
#pragma unroll
                for (int fn = 0; fn < 4; ++fn)
                    dst[fn * 16 + lc] = acc[fm][fn][r];
            }
        }
    }
}

// ---------------- K7: weighted combine (sums KSPLIT partials) ----------------
__global__ void combine_kernel(const float* __restrict__ out2, const int* __restrict__ slot_of,
                               const float* __restrict__ topk_w, float* __restrict__ y) {
    int i = blockIdx.x * 256 + threadIdx.x;   // over NTOK*HD/4
    int t = i >> 8;           // HD/4 = 256 float4 per token
    int c = i & 255;
    int s0 = slot_of[2 * t], s1 = slot_of[2 * t + 1];
    float w0 = topk_w[2 * t], w1 = topk_w[2 * t + 1];
    f32x4 o = {0.f, 0.f, 0.f, 0.f};
#pragma unroll
    for (int ks = 0; ks < KSPLIT; ++ks) {
        const float* p = out2 + (size_t)ks * NSLOT_ALLOC * HD;
        f32x4 a = ((const f32x4*)(p + (size_t)s0 * HD))[c];
        f32x4 b = ((const f32x4*)(p + (size_t)s1 * HD))[c];
#pragma unroll
        for (int j = 0; j < 4; ++j) o[j] += w0 * a[j] + w1 * b[j];
    }
    ((f32x4*)(y + (size_t)t * HD))[c] = o;
}

extern "C" void kernel_launch(void* const* d_in, const int* in_sizes, int n_in,
                              void* d_out, int out_size, void* d_ws, size_t ws_size,
                              hipStream_t stream) {
    (void)in_sizes; (void)n_in; (void)out_size; (void)ws_size;
    const float* x  = (const float*)d_in[0];
    const float* wg = (const float*)d_in[1];
    const float* w1 = (const float*)d_in[2];
    const float* w3 = (const float*)d_in[3];
    const float* w2 = (const float*)d_in[4];
    float* y = (float*)d_out;

    char* ws = (char*)d_ws;
    int*   counts   = (int*)(ws + 0);       // 8 ints
    int*   counts2  = (int*)(ws + 32);      // 8 ints
    int*   offsets  = (int*)(ws + 64);      // 8 ints
    int*   topk_idx = (int*)(ws + 128);                        // 4096 ints
    float* topk_w   = (float*)(ws + 128 + (size_t)NSLOT * 4);  // 4096 floats
    int*   rows     = (int*)(ws + 128 + (size_t)NSLOT * 8);    // 4224 ints
    int*   slot_of  = (int*)(ws + 128 + (size_t)NSLOT * 8 + (size_t)NSLOT_ALLOC * 4);
    size_t off_xbf = 128 + (size_t)NSLOT * 12 + (size_t)NSLOT_ALLOC * 4;
    off_xbf = (off_xbf + 255) & ~(size_t)255;
    u16* xbf = (u16*)(ws + off_xbf);
    size_t off_h = off_xbf + (size_t)NTOK * HD * 2;
    u16* hbuf = (u16*)(ws + off_h);
    size_t off_w1 = off_h + (size_t)NSLOT_ALLOC * ID * 2;
    u16* w1bf = (u16*)(ws + off_w1);
    size_t off_w3 = off_w1 + (size_t)WN * 2;
    u16* w3bf = (u16*)(ws + off_w3);
    size_t off_w2 = off_w3 + (size_t)WN * 2;
    u16* w2bf = (u16*)(ws + off_w2);
    size_t off_o2 = off_w2 + (size_t)WN * 2;
    float* out2 = (float*)(ws + off_o2);    // KSPLIT partial buffers

    init_kernel<<<1, 64, 0, stream>>>(counts);
    router_kernel<<<NTOK, 64, 0, stream>>>(x, wg, topk_idx, topk_w, counts);
    scan_kernel<<<1, 128, 0, stream>>>(counts, offsets, rows);
    assign_kernel<<<NSLOT / 256, 256, 0, stream>>>(topk_idx, offsets, counts2, rows, slot_of);
    cvt3_kernel<<<4096, 256, 0, stream>>>(x, xbf, w1, w1bf, w3, w3bf);
    gemm1_kernel<<<G1_BLOCKS + CVT2_BLOCKS, 256, 0, stream>>>(xbf, w1bf, w3bf, counts, offsets, rows, hbuf, w2, w2bf);
    gemm2_kernel<<<NEXP * (NTOK / 128) * (HD / 128) * KSPLIT, 256, 0, stream>>>(hbuf, w2bf, counts, offsets, out2);
    combine_kernel<<<(NTOK * HD / 4) / 256, 256, 0, stream>>>(out2, slot_of, topk_w, y);
}

// Round 10
// 344.797 us; speedup vs baseline: 1.1664x; 1.0012x over previous
//
#include <hip/hip_runtime.h>
#include <hip/hip_bf16.h>
#include <stdint.h>

#define NEXP 8
#define HD 1024
#define ID 3584
#define NTOK 2048
#define NSLOT 4096          // NTOK * TOPK
#define SLOT_PAD 128
#define NSLOT_ALLOC (NSLOT + SLOT_PAD)
#define WN (NEXP * ID * HD)   // elements per weight tensor = 29,360,128
#define KSPLIT 4
#define KLEN (ID / KSPLIT)    // 896

typedef unsigned short u16;
typedef __attribute__((ext_vector_type(8))) short s16x8;
typedef __attribute__((ext_vector_type(4))) short s16x4;
typedef __attribute__((ext_vector_type(4))) float f32x4;

__device__ __forceinline__ u16 f2bf(float f) {
    __hip_bfloat16 h = __float2bfloat16(f);   // RNE
    union { __hip_bfloat16 h; u16 u; } v; v.h = h; return v.u;
}

__device__ __forceinline__ s16x8 cvt8(f32x4 a, f32x4 b) {
    s16x8 o;
    o[0]=(short)f2bf(a[0]); o[1]=(short)f2bf(a[1]); o[2]=(short)f2bf(a[2]); o[3]=(short)f2bf(a[3]);
    o[4]=(short)f2bf(b[0]); o[5]=(short)f2bf(b[1]); o[6]=(short)f2bf(b[2]); o[7]=(short)f2bf(b[3]);
    return o;
}

__device__ __forceinline__ void glds16(const void* g, void* l) {
    __builtin_amdgcn_global_load_lds((const __attribute__((address_space(1))) unsigned*)g,
                                     (__attribute__((address_space(3))) unsigned*)l, 16, 0, 0);
}

// ---------------- K0: zero counters ----------------
__global__ void init_kernel(int* __restrict__ counts) {
    if (threadIdx.x < 16) counts[threadIdx.x] = 0;   // counts[8] + counts2[8]
}

// ---------------- K1: router (fp32, exact top-2) ----------------
__global__ void router_kernel(const float* __restrict__ x, const float* __restrict__ wg,
                              int* __restrict__ topk_idx, float* __restrict__ topk_w,
                              int* __restrict__ counts) {
    int t = blockIdx.x;
    int lane = threadIdx.x;   // 64 threads = 1 wave
    const float* xr = x + (size_t)t * HD;
    float acc[NEXP];
#pragma unroll
    for (int e = 0; e < NEXP; ++e) acc[e] = 0.f;
#pragma unroll
    for (int i = 0; i < HD / 256; ++i) {
        int h = i * 256 + lane * 4;
        f32x4 xv = *(const f32x4*)(xr + h);
#pragma unroll
        for (int e = 0; e < NEXP; ++e) {
            f32x4 wv = *(const f32x4*)(wg + e * HD + h);
            acc[e] += xv[0]*wv[0] + xv[1]*wv[1] + xv[2]*wv[2] + xv[3]*wv[3];
        }
    }
#pragma unroll
    for (int e = 0; e < NEXP; ++e) {
#pragma unroll
        for (int s = 32; s > 0; s >>= 1) acc[e] += __shfl_xor(acc[e], s, 64);
    }
    if (lane == 0) {
        int b0 = 0; float l0 = acc[0];
#pragma unroll
        for (int e = 1; e < NEXP; ++e) if (acc[e] > l0) { l0 = acc[e]; b0 = e; }
        int b1 = (b0 == 0) ? 1 : 0; float l1 = acc[b1];
#pragma unroll
        for (int e = 0; e < NEXP; ++e) {
            if (e == b0 || e == b1) continue;
            if (acc[e] > l1) { l1 = acc[e]; b1 = e; }
        }
        float w0 = 1.f / (1.f + expf(l1 - l0));   // renormalized top-2 softmax
        float w1 = 1.f - w0;
        topk_idx[2 * t] = b0; topk_idx[2 * t + 1] = b1;
        topk_w[2 * t] = w0;  topk_w[2 * t + 1] = w1;
        atomicAdd(&counts[b0], 1);
        atomicAdd(&counts[b1], 1);
    }
}

// ---------------- K2: exclusive scan + pad rows ----------------
__global__ void scan_kernel(const int* __restrict__ counts, int* __restrict__ offsets,
                            int* __restrict__ rows) {
    if (threadIdx.x == 0) {
        int off = 0;
#pragma unroll
        for (int e = 0; e < NEXP; ++e) { offsets[e] = off; off += counts[e]; }
    }
    if (threadIdx.x < SLOT_PAD) rows[NSLOT + threadIdx.x] = 0;
}

// ---------------- K3: slot assignment ----------------
__global__ void assign_kernel(const int* __restrict__ topk_idx, const int* __restrict__ offsets,
                              int* __restrict__ counts2, int* __restrict__ rows,
                              int* __restrict__ slot_of) {
    int i = blockIdx.x * 256 + threadIdx.x;   // 0..4095
    int e = topk_idx[i];
    int pos = atomicAdd(&counts2[e], 1);
    int slot = offsets[e] + pos;
    rows[slot] = i >> 1;       // token id
    slot_of[i] = slot;
}

// ---------------- K4: fused fp32->bf16 for x, w1, w3 (one dispatch) ----------------
__global__ __launch_bounds__(256)
void cvt3_kernel(const float* __restrict__ x, u16* __restrict__ xbf,
                 const float* __restrict__ w1, u16* __restrict__ w1bf,
                 const float* __restrict__ w3, u16* __restrict__ w3bf) {
    const int NX = NTOK * HD / 8, NW = WN / 8;
    int stride = gridDim.x * 256;
    for (int i = blockIdx.x * 256 + threadIdx.x; i < NX + 2 * NW; i += stride) {
        const float* s; u16* d; int j;
        if (i < NX)            { s = x;  d = xbf;  j = i; }
        else if (i < NX + NW)  { s = w1; d = w1bf; j = i - NX; }
        else                   { s = w3; d = w3bf; j = i - NX - NW; }
        f32x4 v0 = ((const f32x4*)s)[2 * j];
        f32x4 v1 = ((const f32x4*)s)[2 * j + 1];
        ((s16x8*)d)[j] = cvt8(v0, v1);
    }
}

// ---------------- K5: FAT kernel: fused GEMM1 (g,u)+SwiGLU -> h  ||  w2 fp32->bf16 ----------------
// 8-wave 512-thread blocks, 128x128 tile, wave tile 64x32 (dual acc = 64 regs/lane,
// half of R9) -> 2 blocks/CU = 16 waves/CU resident. Zero-conflict swizzle + T1
// panel-XCD remap retained from R9 (FETCH verified ~ideal).
#define G1_BLOCKS (NEXP * (NTOK / 128) * (ID / 128))   // 3584
#define CVT2_BLOCKS 1024
__global__ __launch_bounds__(512, 4)
void gemm1_kernel(const u16* __restrict__ xbf, const u16* __restrict__ w1bf,
                  const u16* __restrict__ w3bf, const int* __restrict__ counts,
                  const int* __restrict__ offsets, const int* __restrict__ rows,
                  u16* __restrict__ hbuf,
                  const float* __restrict__ w2, u16* __restrict__ w2bf) {
    __shared__ u16 As[128][32];    // 8 KB
    __shared__ u16 B1s[128][32];   // 8 KB
    __shared__ u16 B3s[128][32];   // 8 KB

    if (blockIdx.x >= G1_BLOCKS) {
        // ---- side job: convert w2 to bf16 (overlaps with GEMM1 blocks) ----
        const int stride = CVT2_BLOCKS * 512;
        for (int i = (blockIdx.x - G1_BLOCKS) * 512 + threadIdx.x; i < WN / 8; i += stride) {
            f32x4 v0 = ((const f32x4*)w2)[2 * i];
            f32x4 v1 = ((const f32x4*)w2)[2 * i + 1];
            ((s16x8*)w2bf)[i] = cvt8(v0, v1);
        }
        return;
    }

    // T1 panel-XCD decode: panel g = gq*8 + (bid&7), mt = (bid>>3)&15.
    int bid = blockIdx.x;
    int gq = bid >> 7;            // 0..27
    int rm = bid & 127;
    int mt = rm >> 3;             // 0..15
    int g  = gq * 8 + (rm & 7);   // 0..223
    int e  = g / 28;              // NT = ID/128 = 28
    int nt = g - e * 28;

    int n_e = counts[e];
    int m0 = mt * 128;
    if (m0 >= n_e) return;
    int off = offsets[e];
    int n0 = nt * 128;

    int tid = threadIdx.x;
    int lane = tid & 63;
    int wid = tid >> 6;           // 0..7

    // staging: wave wid stages the 16-row slab wid of each array (3 glds/wave).
    // physical granule lane&3, source granule (lane&3)^((srow>>1)&3) (T2 pre-swizzle).
    int srow = wid * 16 + (lane >> 2);
    int chunk = ((lane & 3) ^ ((srow >> 1) & 3)) * 8;

    int tokA = rows[off + m0 + srow];
    const u16* srcA  = xbf + (size_t)tokA * HD + chunk;
    const u16* srcB1 = w1bf + ((size_t)e * ID + n0 + srow) * HD + chunk;
    const u16* srcB3 = w3bf + ((size_t)e * ID + n0 + srow) * HD + chunk;

    f32x4 accg[4][2] = {}, accu[4][2] = {};
    int wm = (wid >> 2) * 64;     // 0 / 64
    int wn = (wid & 3) * 32;      // 0 / 32 / 64 / 96
    int lr = lane & 15;
    int k8sw = ((lane >> 4) ^ ((lr >> 1) & 3)) * 8;   // inverse swizzle on ds_read
                                                       // (slab base %16==0 keeps algebra)

    for (int k0 = 0; k0 < HD; k0 += 32) {
        glds16(srcA + k0,  &As[wid * 16][0]);
        glds16(srcB1 + k0, &B1s[wid * 16][0]);
        glds16(srcB3 + k0, &B3s[wid * 16][0]);
        __syncthreads();
        s16x8 a[4], b1[2], b3[2];
#pragma unroll
        for (int f = 0; f < 4; ++f)
            a[f] = *(const s16x8*)&As[wm + f * 16 + lr][k8sw];
#pragma unroll
        for (int f = 0; f < 2; ++f) {
            b1[f] = *(const s16x8*)&B1s[wn + f * 16 + lr][k8sw];
            b3[f] = *(const s16x8*)&B3s[wn + f * 16 + lr][k8sw];
        }
#pragma unroll
        for (int fm = 0; fm < 4; ++fm)
#pragma unroll
            for (int fn = 0; fn < 2; ++fn) {
                accg[fm][fn] = __builtin_amdgcn_mfma_f32_16x16x32_bf16(a[fm], b1[fn], accg[fm][fn], 0, 0, 0);
                accu[fm][fn] = __builtin_amdgcn_mfma_f32_16x16x32_bf16(a[fm], b3[fn], accu[fm][fn], 0, 0, 0);
            }
        __syncthreads();
    }

    // epilogue: SwiGLU + bf16 store
    int lc = lane & 15;
    int lr4 = (lane >> 4) * 4;
#pragma unroll
    for (int fm = 0; fm < 4; ++fm) {
#pragma unroll
        for (int r = 0; r < 4; ++r) {
            int row = wm + fm * 16 + lr4 + r;
            if (m0 + row < n_e) {
                size_t base = (size_t)(off + m0 + row) * ID + n0 + wn;
#pragma unroll
                for (int fn = 0; fn < 2; ++fn) {
                    float g2 = accg[fm][fn][r];
                    float u = accu[fm][fn][r];
                    float hv = g2 * u / (1.f + expf(-g2));   // silu(g)*u
                    hbuf[base + fn * 16 + lc] = f2bf(hv);
                }
            }
        }
    }
}

// ---------------- K6: GEMM2 h @ w2bf^T -> per-slot fp32, split-K x4, 8-wave ----------------
// T1 expert-XCD remap: bid%8 = e. Wave tile 64x32, acc = 32 regs/lane.
__global__ __launch_bounds__(512, 4)
void gemm2_kernel(const u16* __restrict__ hbuf, const u16* __restrict__ w2bf,
                  const int* __restrict__ counts, const int* __restrict__ offsets,
                  float* __restrict__ out2) {
    int bid = blockIdx.x;
    int e = bid & 7;
    int inner = bid >> 3;        // 0..511
    int mt = inner >> 5;         // 0..15
    int r2 = inner & 31;
    int nt = r2 >> 2;            // 0..7
    int ks = r2 & 3;             // 0..3

    int n_e = counts[e];
    int m0 = mt * 128;
    if (m0 >= n_e) return;
    int off = offsets[e];
    int n0 = nt * 128;
    int kbase = ks * KLEN;

    __shared__ u16 As[128][32];   // 8 KB
    __shared__ u16 Bs[128][32];   // 8 KB

    int tid = threadIdx.x;
    int lane = tid & 63;
    int wid = tid >> 6;           // 0..7

    int srow = wid * 16 + (lane >> 2);
    int chunk = ((lane & 3) ^ ((srow >> 1) & 3)) * 8;
    const u16* srcA = hbuf + (size_t)(off + m0 + srow) * ID + kbase + chunk;
    const u16* srcB = w2bf + ((size_t)e * HD + n0 + srow) * ID + kbase + chunk;

    f32x4 acc[4][2] = {};
    int wm = (wid >> 2) * 64;
    int wn = (wid & 3) * 32;
    int lr = lane & 15;
    int k8sw = ((lane >> 4) ^ ((lr >> 1) & 3)) * 8;

    for (int k0 = 0; k0 < KLEN; k0 += 32) {
        glds16(srcA + k0, &As[wid * 16][0]);
        glds16(srcB + k0, &Bs[wid * 16][0]);
        __syncthreads();
        s16x8 a[4], b[2];
#pragma unroll
        for (int f = 0; f < 4; ++f)
            a[f] = *(const s16x8*)&As[wm + f * 16 + lr][k8sw];
#pragma unroll
        for (int f = 0; f < 2; ++f)
            b[f] = *(const s16x8*)&Bs[wn + f * 16 + lr][k8sw];
#pragma unroll
        for (int fm = 0; fm < 4; ++fm)
#pragma unroll
            for (int fn = 0; fn < 2; ++fn)
                acc[fm][fn] = __builtin_amdgcn_mfma_f32_16x16x32_bf16(a[fm], b[fn], acc[fm][fn], 0, 0, 0);
        __syncthreads();
    }

    float* outp = out2 + (size_t)ks * NSLOT_ALLOC * HD;
    int lc = lane & 15;
    int lr4 = (lane >> 4) * 4;
#pragma unroll
    for (int fm = 0; fm < 4; ++fm) {
#pragma unroll
        for (int r = 0; r < 4; ++r) {
            int row = wm + fm * 16 + lr4 + r;
            if (m0 + row < n_e) {
                float* dst = outp + (size_t)(off + m0 + row) * HD + n0 + wn;
#pragma unroll
                for (int fn = 0; fn < 2; ++fn)
                    dst[fn * 16 + lc] = acc[fm][fn][r];
            }
        }
    }
}

// ---------------- K7: weighted combine (sums KSPLIT partials) ----------------
__global__ void combine_kernel(const float* __restrict__ out2, const int* __restrict__ slot_of,
                               const float* __restrict__ topk_w, float* __restrict__ y) {
    int i = blockIdx.x * 256 + threadIdx.x;   // over NTOK*HD/4
    int t = i >> 8;           // HD/4 = 256 float4 per token
    int c = i & 255;
    int s0 = slot_of[2 * t], s1 = slot_of[2 * t + 1];
    float w0 = topk_w[2 * t], w1 = topk_w[2 * t + 1];
    f32x4 o = {0.f, 0.f, 0.f, 0.f};
#pragma unroll
    for (int ks = 0; ks < KSPLIT; ++ks) {
        const float* p = out2 + (size_t)ks * NSLOT_ALLOC * HD;
        f32x4 a = ((const f32x4*)(p + (size_t)s0 * HD))[c];
        f32x4 b = ((const f32x4*)(p + (size_t)s1 * HD))[c];
#pragma unroll
        for (int j = 0; j < 4; ++j) o[j] += w0 * a[j] + w1 * b[j];
    }
    ((f32x4*)(y + (size_t)t * HD))[c] = o;
}

extern "C" void kernel_launch(void* const* d_in, const int* in_sizes, int n_in,
                              void* d_out, int out_size, void* d_ws, size_t ws_size,
                              hipStream_t stream) {
    (void)in_sizes; (void)n_in; (void)out_size; (void)ws_size;
    const float* x  = (const float*)d_in[0];
    const float* wg = (const float*)d_in[1];
    const float* w1 = (const float*)d_in[2];
    const float* w3 = (const float*)d_in[3];
    const float* w2 = (const float*)d_in[4];
    float* y = (float*)d_out;

    char* ws = (char*)d_ws;
    int*   counts   = (int*)(ws + 0);       // 8 ints
    int*   counts2  = (int*)(ws + 32);      // 8 ints
    int*   offsets  = (int*)(ws + 64);      // 8 ints
    int*   topk_idx = (int*)(ws + 128);                        // 4096 ints
    float* topk_w   = (float*)(ws + 128 + (size_t)NSLOT * 4);  // 4096 floats
    int*   rows     = (int*)(ws + 128 + (size_t)NSLOT * 8);    // 4224 ints
    int*   slot_of  = (int*)(ws + 128 + (size_t)NSLOT * 8 + (size_t)NSLOT_ALLOC * 4);
    size_t off_xbf = 128 + (size_t)NSLOT * 12 + (size_t)NSLOT_ALLOC * 4;
    off_xbf = (off_xbf + 255) & ~(size_t)255;
    u16* xbf = (u16*)(ws + off_xbf);
    size_t off_h = off_xbf + (size_t)NTOK * HD * 2;
    u16* hbuf = (u16*)(ws + off_h);
    size_t off_w1 = off_h + (size_t)NSLOT_ALLOC * ID * 2;
    u16* w1bf = (u16*)(ws + off_w1);
    size_t off_w3 = off_w1 + (size_t)WN * 2;
    u16* w3bf = (u16*)(ws + off_w3);
    size_t off_w2 = off_w3 + (size_t)WN * 2;
    u16* w2bf = (u16*)(ws + off_w2);
    size_t off_o2 = off_w2 + (size_t)WN * 2;
    float* out2 = (float*)(ws + off_o2);    // KSPLIT partial buffers

    init_kernel<<<1, 64, 0, stream>>>(counts);
    router_kernel<<<NTOK, 64, 0, stream>>>(x, wg, topk_idx, topk_w, counts);
    scan_kernel<<<1, 128, 0, stream>>>(counts, offsets, rows);
    assign_kernel<<<NSLOT / 256, 256, 0, stream>>>(topk_idx, offsets, counts2, rows, slot_of);
    cvt3_kernel<<<4096, 256, 0, stream>>>(x, xbf, w1, w1bf, w3, w3bf);
    gemm1_kernel<<<G1_BLOCKS + CVT2_BLOCKS, 512, 0, stream>>>(xbf, w1bf, w3bf, counts, offsets, rows, hbuf, w2, w2bf);
    gemm2_kernel<<<NEXP * (NTOK / 128) * (HD / 128) * KSPLIT, 512, 0, stream>>>(hbuf, w2bf, counts, offsets, out2);
    combine_kernel<<<(NTOK * HD / 4) / 256, 256, 0, stream>>>(out2, slot_of, topk_w, y);
}